// Round 5
// baseline (109.086 us; speedup 1.0000x reference)
//
#include <hip/hip_runtime.h>
#include <math.h>

#define TBL_N     1024
#define TBL_MAXU  1023.999f
#define KIDX      44.36141955583649f     // (TBL_N/16) * ln2 — maps l to table index
#define LOG2E     1.44269504088896340736f
#define INV_BATCH (1.0f / 12.0f)

// ================= compile-time table: F(l) on l in [0,16], 1025 knots ====
// F(l) = e*(l-tau) + 0.25                 for l <  l0 = tau - 1/(2e)
//      = ((1+W(2(l-tau)))^2 - 1) / 4      for l >= l0   (exact identity)
struct TblData { float v[TBL_N + 1]; };

constexpr double k_ln2 = 0.69314718055994530942;
constexpr double k_e   = 2.71828182845904523536;

constexpr double cexp(double x) {
    double t = x * 1.44269504088896340736;
    int n = (int)(t + (t >= 0 ? 0.5 : -0.5));
    double r = x - (double)n * k_ln2;
    double s = 1.0, term = 1.0;
    for (int i = 1; i <= 13; ++i) { term *= r / i; s += term; }
    double p = 1.0;
    if (n >= 0) for (int i = 0; i <  n; ++i) p *= 2.0;
    else        for (int i = 0; i < -n; ++i) p *= 0.5;
    return s * p;
}
constexpr double csqrt_(double x) {
    double r = x > 1.0 ? x : 1.0;
    for (int i = 0; i < 24; ++i) r = 0.5 * (r + x / r);
    return r;
}
constexpr double clog_(double x) {
    int n = 0; double m = x;
    while (m >= 2.0) { m *= 0.5; ++n; }
    while (m <  1.0) { m *= 2.0; --n; }
    double z = (m - 1.0) / (m + 1.0), z2 = z * z, s = 0.0, t = z;
    for (int i = 0; i < 17; ++i) { s += t / (2 * i + 1); t *= z2; }
    return 2.0 * s + (double)n * k_ln2;
}
constexpr TblData make_table() {
    TblData T{};
    for (int i = 0; i <= TBL_N; ++i) {
        double l   = (double)i * (16.0 / TBL_N);
        double tau = k_ln2;
        double l0  = tau - 1.0 / (2.0 * k_e);
        double F;
        if (l < l0) {
            F = k_e * (l - tau) + 0.25;
        } else {
            double y = 2.0 * (l - tau);
            double ylim = -1.0 / k_e;
            if (y < ylim) y = ylim;
            double w = (y < 3.0) ? (csqrt_(2.0 * (k_e * y + 1.0)) - 1.0)
                                 : clog_(y);
            for (int it = 0; it < 4; ++it) {
                double ew  = cexp(w);
                double f   = w * ew - y;
                double wp1 = w + 1.0;
                double den = ew * wp1 - (w + 2.0) * f / (2.0 * wp1 + 1e-300);
                if (f != 0.0) w -= f / den;
            }
            F = 0.25 * ((1.0 + w) * (1.0 + w) - 1.0);
        }
        T.v[i] = (float)F;
    }
    return T;
}
__device__ __constant__ TblData c_tbl = make_table();

// ================= main pass =============================================
__shared__ float s_tbl[TBL_N + 1];                // 4.1 KB

__device__ __forceinline__ float tbl_eval(float u) {
    u = fminf(u, TBL_MAXU);                        // u >= 0 guaranteed
    int   i = (int)u;
    float f = u - (float)i;
    float t0 = s_tbl[i];
    float t1 = s_tbl[i + 1];
    return fmaf(f, t1 - t0, t0);
}

// l*idx_scale via 2 exp + 1 log: l = ln(1 + e^{o1-xl} + e^{o2-xl})
template<int L>
__device__ __forceinline__ float row_fixed(float a, float b, float c) {
    float xl = (L == 0) ? a : ((L == 1) ? b : c);
    float o1 = (L == 0) ? b : a;
    float o2 = (L == 2) ? b : c;
    float e1 = exp2f((o1 - xl) * LOG2E);
    float e2 = exp2f((o2 - xl) * LOG2E);
    float u  = __log2f(1.0f + e1 + e2) * KIDX;
    return tbl_eval(u);
}

__device__ __forceinline__ float row_gen(float a, float b, float c, int lab) {
    float xl = (lab == 0) ? a : ((lab == 1) ? b : c);
    float o1 = (lab == 0) ? b : a;
    float o2 = (lab == 2) ? b : c;
    float e1 = exp2f((o1 - xl) * LOG2E);
    float e2 = exp2f((o2 - xl) * LOG2E);
    float u  = __log2f(1.0f + e1 + e2) * KIDX;
    return tbl_eval(u);
}

template<int L>
__device__ __forceinline__ float quad_sum(float4 f0, float4 f1, float4 f2) {
    return row_fixed<L>(f0.x, f0.y, f0.z) + row_fixed<L>(f0.w, f1.x, f1.y)
         + row_fixed<L>(f1.z, f1.w, f2.x) + row_fixed<L>(f2.y, f2.z, f2.w);
}

__device__ __forceinline__ float block_reduce(float acc) {
#pragma unroll
    for (int off = 32; off > 0; off >>= 1)
        acc += __shfl_down(acc, off, 64);
    __shared__ float sacc[4];
    int lane = threadIdx.x & 63;
    int wv   = threadIdx.x >> 6;
    if (lane == 0) sacc[wv] = acc;
    __syncthreads();
    float s = 0.0f;
    if (threadIdx.x == 0)
        s = sacc[0] + sacc[1] + sacc[2] + sacc[3];
    return s;
}

__global__ __launch_bounds__(256) void superloss_partial(
        const float* __restrict__ x,
        const int* __restrict__ pn0,
        const int* __restrict__ pn1,
        float* __restrict__ partial,
        int nrows) {
    for (int i = threadIdx.x; i <= TBL_N; i += 256)
        s_tbl[i] = c_tbl.v[i];
    __syncthreads();

    const int n0  = *pn0;
    const int n01 = n0 + *pn1;

    const int gid    = blockIdx.x * 256 + threadIdx.x;
    const int stride = gridDim.x * 256;
    const int nq     = nrows >> 2;

    float acc = 0.0f;

    if (((n0 | n01) & 3) == 0) {
        // region boundaries quad-aligned: one loop, label fixed per region,
        // all 9 loads issued before any compute (max MLP)
        const int nq0 = n0 >> 2, nq1 = n01 >> 2;
        int q0 = gid, q1 = nq0 + gid, q2 = nq1 + gid;
        for (;;) {
            bool h0 = q0 < nq0, h1 = q1 < nq1, h2 = q2 < nq;
            if (!(h0 || h1 || h2)) break;
            float4 A0, A1, A2, B0, B1, B2, C0, C1, C2;
            if (h0) { const float4* p = (const float4*)x + 3 * (size_t)q0; A0 = p[0]; A1 = p[1]; A2 = p[2]; }
            if (h1) { const float4* p = (const float4*)x + 3 * (size_t)q1; B0 = p[0]; B1 = p[1]; B2 = p[2]; }
            if (h2) { const float4* p = (const float4*)x + 3 * (size_t)q2; C0 = p[0]; C1 = p[1]; C2 = p[2]; }
            if (h0) acc += quad_sum<0>(A0, A1, A2);
            if (h1) acc += quad_sum<1>(B0, B1, B2);
            if (h2) acc += quad_sum<2>(C0, C1, C2);
            q0 += stride; q1 += stride; q2 += stride;
        }
        for (int r = (nq << 2) + gid; r < nrows; r += stride) {
            int lab = (r >= n0) + (r >= n01);
            acc += row_gen(x[3 * (size_t)r], x[3 * (size_t)r + 1],
                           x[3 * (size_t)r + 2], lab);
        }
    } else {
        for (int r = gid; r < nrows; r += stride) {
            int lab = (r >= n0) + (r >= n01);
            acc += row_gen(x[3 * (size_t)r], x[3 * (size_t)r + 1],
                           x[3 * (size_t)r + 2], lab);
        }
    }

    float s = block_reduce(acc);
    if (threadIdx.x == 0)
        partial[blockIdx.x] = s;
}

__global__ __launch_bounds__(256) void superloss_final(
        const float* __restrict__ partial,
        int np,
        float* __restrict__ out) {
    float acc = 0.0f;
    for (int i = threadIdx.x; i < np; i += 256)
        acc += partial[i];
    float s = block_reduce(acc);
    if (threadIdx.x == 0)
        out[0] = s * INV_BATCH;
}

extern "C" void kernel_launch(void* const* d_in, const int* in_sizes, int n_in,
                              void* d_out, int out_size, void* d_ws, size_t ws_size,
                              hipStream_t stream) {
    const float* x   = (const float*)d_in[0];
    const int*   pn0 = (const int*)d_in[1];
    const int*   pn1 = (const int*)d_in[2];

    const int nrows = in_sizes[0] / 3;

    int nblk = 2048;
    size_t need = (size_t)nblk * sizeof(float);
    if (ws_size < need) {
        nblk = (int)(ws_size / sizeof(float));
        if (nblk < 1) nblk = 1;
    }

    float* partial = (float*)d_ws;
    superloss_partial<<<nblk, 256, 0, stream>>>(x, pn0, pn1, partial, nrows);
    superloss_final<<<1, 256, 0, stream>>>(partial, nblk, (float*)d_out);
}

// Round 6
// 108.755 us; speedup vs baseline: 1.0030x; 1.0030x over previous
//
#include <hip/hip_runtime.h>
#include <math.h>

#define TBL_N     1024
#define TBL_MAXU  1023.999f
#define KIDX      44.36141955583649f     // (TBL_N/16) * ln2 — maps log2(s) to table index
#define INV_BATCH (1.0 / 12.0)

#define ROWS_PER_TILE 1024               // 768 float4 = 12 KB LDS
#define F4_PER_TILE   768

// ================= compile-time table ====================================
// F(l)/12, F = e*(l-tau) + 0.25             for l <  l0 = tau - 1/(2e)
//            = ((1+W(2(l-tau)))^2 - 1)/4    for l >= l0  (exact identity)
struct TblData { float v[TBL_N + 1]; };

constexpr double k_ln2 = 0.69314718055994530942;
constexpr double k_e   = 2.71828182845904523536;

constexpr double cexp(double x) {
    double t = x * 1.44269504088896340736;
    int n = (int)(t + (t >= 0 ? 0.5 : -0.5));
    double r = x - (double)n * k_ln2;
    double s = 1.0, term = 1.0;
    for (int i = 1; i <= 13; ++i) { term *= r / i; s += term; }
    double p = 1.0;
    if (n >= 0) for (int i = 0; i <  n; ++i) p *= 2.0;
    else        for (int i = 0; i < -n; ++i) p *= 0.5;
    return s * p;
}
constexpr double csqrt_(double x) {
    double r = x > 1.0 ? x : 1.0;
    for (int i = 0; i < 24; ++i) r = 0.5 * (r + x / r);
    return r;
}
constexpr double clog_(double x) {
    int n = 0; double m = x;
    while (m >= 2.0) { m *= 0.5; ++n; }
    while (m <  1.0) { m *= 2.0; --n; }
    double z = (m - 1.0) / (m + 1.0), z2 = z * z, s = 0.0, t = z;
    for (int i = 0; i < 17; ++i) { s += t / (2 * i + 1); t *= z2; }
    return 2.0 * s + (double)n * k_ln2;
}
constexpr TblData make_table() {
    TblData T{};
    for (int i = 0; i <= TBL_N; ++i) {
        double l   = (double)i * (16.0 / TBL_N);
        double tau = k_ln2;
        double l0  = tau - 1.0 / (2.0 * k_e);
        double F;
        if (l < l0) {
            F = k_e * (l - tau) + 0.25;
        } else {
            double y = 2.0 * (l - tau);
            double ylim = -1.0 / k_e;
            if (y < ylim) y = ylim;
            double w = (y < 3.0) ? (csqrt_(2.0 * (k_e * y + 1.0)) - 1.0)
                                 : clog_(y);
            for (int it = 0; it < 4; ++it) {
                double ew  = cexp(w);
                double f   = w * ew - y;
                double wp1 = w + 1.0;
                double den = ew * wp1 - (w + 2.0) * f / (2.0 * wp1 + 1e-300);
                if (f != 0.0) w -= f / den;
            }
            F = 0.25 * ((1.0 + w) * (1.0 + w) - 1.0);
        }
        T.v[i] = (float)(F * INV_BATCH);   // 1/BATCH baked in
    }
    return T;
}
__device__ __constant__ TblData c_tbl = make_table();

// ================= helpers ===============================================
__device__ __forceinline__ float tbl_eval(const float* __restrict__ tbl, float u) {
    u = fminf(u, TBL_MAXU);                // u >= 0 guaranteed (log2(s>=1))
    int   i = (int)u;
    float f = u - (float)i;
    float t0 = tbl[i];
    float t1 = tbl[i + 1];
    return fmaf(f, t1 - t0, t0);
}

__device__ __forceinline__ float row_eval(const float* __restrict__ tbl,
                                          float a, float b, float c, int lab) {
    float xl = (lab == 0) ? a : ((lab == 1) ? b : c);
    float o1 = (lab == 0) ? b : a;
    float o2 = (lab == 2) ? b : c;
    float e1 = __expf(o1 - xl);
    float e2 = __expf(o2 - xl);
    float u  = __log2f(1.0f + e1 + e2) * KIDX;
    return tbl_eval(tbl, u);
}

__device__ __forceinline__ float block_reduce(float acc) {
#pragma unroll
    for (int off = 32; off > 0; off >>= 1)
        acc += __shfl_down(acc, off, 64);
    __shared__ float sacc[4];
    int lane = threadIdx.x & 63;
    int wv   = threadIdx.x >> 6;
    if (lane == 0) sacc[wv] = acc;
    __syncthreads();
    float s = 0.0f;
    if (threadIdx.x == 0)
        s = sacc[0] + sacc[1] + sacc[2] + sacc[3];
    return s;
}

// ================= main pass =============================================
__global__ __launch_bounds__(256) void superloss_partial(
        const float* __restrict__ x,
        const int* __restrict__ pn0,
        const int* __restrict__ pn1,
        float* __restrict__ partial,
        int nrows) {
    __shared__ float  s_tbl[TBL_N + 1];        // 4.1 KB
    __shared__ float4 s_buf[F4_PER_TILE];      // 12 KB

    const int tid = threadIdx.x;
    for (int i = tid; i <= TBL_N; i += 256)
        s_tbl[i] = c_tbl.v[i];

    const int n0  = *pn0;
    const int n01 = n0 + *pn1;

    const int ntiles = nrows / ROWS_PER_TILE;  // full tiles
    float acc = 0.0f;

    for (int tile = blockIdx.x; tile < ntiles; tile += gridDim.x) {
        // stage: 768 float4, fully coalesced (lane-consecutive)
        const float4* src = (const float4*)x + (size_t)tile * F4_PER_TILE;
        float4 v0 = src[tid];
        float4 v1 = src[tid + 256];
        float4 v2 = src[tid + 512];
        __syncthreads();                       // protect previous consume
        s_buf[tid]       = v0;
        s_buf[tid + 256] = v1;
        s_buf[tid + 512] = v2;
        __syncthreads();

        // consume: thread t owns rows 4t..4t+3 of this tile
        float4 q0 = s_buf[3 * tid];            // ds_read_b128, bank-clean
        float4 q1 = s_buf[3 * tid + 1];
        float4 q2 = s_buf[3 * tid + 2];

        int r = tile * ROWS_PER_TILE + 4 * tid;
        int l0 = (r     >= n0) + (r     >= n01);
        int l1 = (r + 1 >= n0) + (r + 1 >= n01);
        int l2 = (r + 2 >= n0) + (r + 2 >= n01);
        int l3 = (r + 3 >= n0) + (r + 3 >= n01);

        acc += row_eval(s_tbl, q0.x, q0.y, q0.z, l0);
        acc += row_eval(s_tbl, q0.w, q1.x, q1.y, l1);
        acc += row_eval(s_tbl, q1.z, q1.w, q2.x, l2);
        acc += row_eval(s_tbl, q2.y, q2.z, q2.w, l3);
    }

    // tail rows (nrows % 1024), scalar
    const int gid    = blockIdx.x * 256 + tid;
    const int stride = gridDim.x * 256;
    for (int r = ntiles * ROWS_PER_TILE + gid; r < nrows; r += stride) {
        int lab = (r >= n0) + (r >= n01);
        acc += row_eval(s_tbl, x[3 * (size_t)r], x[3 * (size_t)r + 1],
                        x[3 * (size_t)r + 2], lab);
    }

    float s = block_reduce(acc);
    if (threadIdx.x == 0)
        partial[blockIdx.x] = s;
}

__global__ __launch_bounds__(256) void superloss_final(
        const float* __restrict__ partial,
        int np,
        float* __restrict__ out) {
    float acc = 0.0f;
    for (int i = threadIdx.x; i < np; i += 256)
        acc += partial[i];
    float s = block_reduce(acc);
    if (threadIdx.x == 0)
        out[0] = s;                            // 1/BATCH baked into table
}

extern "C" void kernel_launch(void* const* d_in, const int* in_sizes, int n_in,
                              void* d_out, int out_size, void* d_ws, size_t ws_size,
                              hipStream_t stream) {
    const float* x   = (const float*)d_in[0];
    const int*   pn0 = (const int*)d_in[1];
    const int*   pn1 = (const int*)d_in[2];

    const int nrows = in_sizes[0] / 3;

    int nblk = 2048;
    size_t need = (size_t)nblk * sizeof(float);
    if (ws_size < need) {
        nblk = (int)(ws_size / sizeof(float));
        if (nblk < 1) nblk = 1;
    }

    float* partial = (float*)d_ws;
    superloss_partial<<<nblk, 256, 0, stream>>>(x, pn0, pn1, partial, nrows);
    superloss_final<<<1, 256, 0, stream>>>(partial, nblk, (float*)d_out);
}